// Round 3
// baseline (102.554 us; speedup 1.0000x reference)
//
#include <hip/hip_runtime.h>

#define N_TOK 8192
#define D_DIM 1024
#define E_NUM 8
#define D4 (D_DIM / 4)
#define SCAN_BLOCKS 32          // N_TOK / 256

typedef unsigned long long u64;

// Workspace layout:
//   prefix[N]  ulonglong2 : packed within-block exclusive prefix per token (128 KB)
//   bsum[32]   ulonglong2 : packed per-scan-block totals (512 B)
// Packing: lo = experts 0..3, hi = experts 4..7, 16-bit fields each.

// Kernel 1: token-major packed scan. 32 blocks x 256 threads, 1 token/thread.
__global__ __launch_bounds__(256) void scan_kernel(
    const int4* __restrict__ mask4,       // hot_mask as [N][2] int4
    ulonglong2* __restrict__ prefix,      // [N] (ws)
    ulonglong2* __restrict__ bsum)        // [SCAN_BLOCKS] (ws)
{
    const int t   = threadIdx.x;
    const int n   = blockIdx.x * 256 + t;

    const int4 a = mask4[(size_t)n * 2];
    const int4 b = mask4[(size_t)n * 2 + 1];

    u64 lo = (u64)a.x | ((u64)a.y << 16) | ((u64)a.z << 32) | ((u64)a.w << 48);
    u64 hi = (u64)b.x | ((u64)b.y << 16) | ((u64)b.z << 32) | ((u64)b.w << 48);

    __shared__ u64 slo[256], shi[256];
    slo[t] = lo; shi[t] = hi;
    __syncthreads();

    // Hillis-Steele inclusive scan (packed).
    for (int off = 1; off < 256; off <<= 1) {
        u64 plo = 0, phi = 0;
        if (t >= off) { plo = slo[t - off]; phi = shi[t - off]; }
        __syncthreads();
        if (t >= off) { slo[t] += plo; shi[t] += phi; }
        __syncthreads();
    }

    ulonglong2 ex;
    ex.x = slo[t] - lo;       // exclusive
    ex.y = shi[t] - hi;
    prefix[n] = ex;

    if (t == 255) {
        ulonglong2 tot; tot.x = slo[255]; tot.y = shi[255];
        bsum[blockIdx.x] = tot;
    }
}

// Kernel 2: fused scatter + pad-fill + tags + counts.
//   blocks [0, N)       : token n scatter (read x row once, write routed rows).
//   blocks [N, N + E*N) : pad row zero-fill where r >= count_e.
__global__ __launch_bounds__(256) void scatter_kernel(
    const float4* __restrict__ x,         // [N, D/4]
    const float* __restrict__ score,      // [N, E]
    const int4* __restrict__ mask4,       // [N][2] int4
    const ulonglong2* __restrict__ prefix,
    const ulonglong2* __restrict__ bsum,
    float4* __restrict__ out_data,        // [E*N, D/4]
    float* __restrict__ out_tags,         // [E, N]
    float* __restrict__ out_counts)       // [E]
{
    const int b = blockIdx.x;
    const int c = threadIdx.x;

    if (b < N_TOK) {
        const int n   = b;
        const int bid = n >> 8;

        // Global exclusive packed rank for this token (uniform per block).
        u64 plo = prefix[n].x, phi = prefix[n].y;
        for (int k = 0; k < bid; ++k) {
            ulonglong2 s = bsum[k];
            plo += s.x; phi += s.y;
        }

        const int4 ma = mask4[(size_t)n * 2];
        const int4 mb = mask4[(size_t)n * 2 + 1];
        const float4* sc4 = (const float4*)(score + (size_t)n * E_NUM);
        const float4 s0 = sc4[0];
        const float4 s1 = sc4[1];

        const float4 xv = x[(size_t)n * D4 + c];

        const int me[8] = { ma.x, ma.y, ma.z, ma.w, mb.x, mb.y, mb.z, mb.w };
        const float se[8] = { s0.x, s0.y, s0.z, s0.w, s1.x, s1.y, s1.z, s1.w };

        #pragma unroll
        for (int e = 0; e < E_NUM; ++e) {
            if (me[e]) {
                const u64 p = (e < 4) ? plo : phi;
                const int r = (int)((p >> (16 * (e & 3))) & 0xFFFF);
                const float s = se[e];
                float4 v;
                v.x = xv.x * s; v.y = xv.y * s; v.z = xv.z * s; v.w = xv.w * s;
                out_data[((size_t)e * N_TOK + r) * D4 + c] = v;
                if (c == 0) out_tags[(size_t)e * N_TOK + r] = (float)n;
            }
        }
    } else {
        const int row = b - N_TOK;            // e*N + r
        const int e   = row >> 13;
        const int r   = row & (N_TOK - 1);

        // counts output: one designated block, lanes 0..7.
        if (row == 0 && c < E_NUM) {
            const int sh = 16 * (c & 3);
            int cnt = 0;
            for (int k = 0; k < SCAN_BLOCKS; ++k) {
                const u64 p = (c < 4) ? bsum[k].x : bsum[k].y;
                cnt += (int)((p >> sh) & 0xFFFF);
            }
            out_counts[c] = (float)cnt;
        }

        // count for this block's expert (uniform scalar loop).
        const int sh = 16 * (e & 3);
        int cnt = 0;
        for (int k = 0; k < SCAN_BLOCKS; ++k) {
            const u64 p = (e < 4) ? bsum[k].x : bsum[k].y;
            cnt += (int)((p >> sh) & 0xFFFF);
        }

        if (r >= cnt) {
            float4 z; z.x = 0.0f; z.y = 0.0f; z.z = 0.0f; z.w = 0.0f;
            out_data[(size_t)row * D4 + c] = z;
            if (c == 0) out_tags[row] = 0.0f;
        }
    }
}

extern "C" void kernel_launch(void* const* d_in, const int* in_sizes, int n_in,
                              void* d_out, int out_size, void* d_ws, size_t ws_size,
                              hipStream_t stream) {
    const float* x        = (const float*)d_in[0];
    const int*   hot_mask = (const int*)d_in[1];
    const float* score    = (const float*)d_in[2];

    float* out        = (float*)d_out;
    float* out_data   = out;                                  // [E, N, D]
    float* out_tags   = out + (size_t)E_NUM * N_TOK * D_DIM;  // [E, N]
    float* out_counts = out_tags + (size_t)E_NUM * N_TOK;     // [E]

    ulonglong2* prefix = (ulonglong2*)d_ws;                   // [N]
    ulonglong2* bsum   = prefix + N_TOK;                      // [SCAN_BLOCKS]

    scan_kernel<<<SCAN_BLOCKS, 256, 0, stream>>>(
        (const int4*)hot_mask, prefix, bsum);

    scatter_kernel<<<N_TOK + E_NUM * N_TOK, 256, 0, stream>>>(
        (const float4*)x, score, (const int4*)hot_mask, prefix, bsum,
        (float4*)out_data, out_tags, out_counts);
}

// Round 4
// 63.528 us; speedup vs baseline: 1.6143x; 1.6143x over previous
//
#include <hip/hip_runtime.h>

#define N_TOK 8192
#define D_DIM 1024
#define E_NUM 8
#define D4 (D_DIM / 4)
#define SCAN_BLOCKS 32          // N_TOK / 256

typedef unsigned long long u64;

// Workspace layout:
//   prefix[N]     ulonglong2 : packed within-block exclusive prefix (128 KB)
//   bsum[32]      ulonglong2 : packed per-scan-block totals (512 B)
//   dest[N][E]    int        : global rank of token n in expert e, or -1 (256 KB)
//   counts_i[E]   int
// Packing: .x = experts 0..3, .y = experts 4..7, 16-bit fields.

// K1: token-major packed scan. 32 blocks x 256 threads, 1 token/thread.
__global__ __launch_bounds__(256) void scan_kernel(
    const int4* __restrict__ mask4,       // hot_mask as [N][2] int4
    ulonglong2* __restrict__ prefix,      // [N] (ws)
    ulonglong2* __restrict__ bsum)        // [SCAN_BLOCKS] (ws)
{
    const int t = threadIdx.x;
    const int n = blockIdx.x * 256 + t;

    const int4 a = mask4[(size_t)n * 2];
    const int4 b = mask4[(size_t)n * 2 + 1];

    u64 lo = (u64)a.x | ((u64)a.y << 16) | ((u64)a.z << 32) | ((u64)a.w << 48);
    u64 hi = (u64)b.x | ((u64)b.y << 16) | ((u64)b.z << 32) | ((u64)b.w << 48);

    __shared__ u64 slo[256], shi[256];
    slo[t] = lo; shi[t] = hi;
    __syncthreads();

    for (int off = 1; off < 256; off <<= 1) {
        u64 plo = 0, phi = 0;
        if (t >= off) { plo = slo[t - off]; phi = shi[t - off]; }
        __syncthreads();
        if (t >= off) { slo[t] += plo; shi[t] += phi; }
        __syncthreads();
    }

    ulonglong2 ex;
    ex.x = slo[t] - lo;       // exclusive
    ex.y = shi[t] - hi;
    prefix[n] = ex;

    if (t == 255) {
        ulonglong2 tot; tot.x = slo[255]; tot.y = shi[255];
        bsum[blockIdx.x] = tot;
    }
}

// K2: finalize. 32 blocks x 256 threads, 1 token/thread.
// Computes global ranks, writes dest (coalesced int4 x2), scatters tags,
// fills tag pad region, writes counts.
__global__ __launch_bounds__(256) void finalize_kernel(
    const int4* __restrict__ mask4,
    const ulonglong2* __restrict__ prefix,
    const ulonglong2* __restrict__ bsum,
    int* __restrict__ dest,               // [N, E] (ws)
    int* __restrict__ counts_i,           // [E]    (ws)
    float* __restrict__ out_tags,         // [E, N]
    float* __restrict__ out_counts)       // [E]
{
    const int bid = blockIdx.x;
    const int t   = threadIdx.x;
    const int n   = bid * 256 + t;

    // Block offset and grand totals from bsum (512 B, L2-hot, unrolled).
    u64 blo = 0, bhi = 0, tlo = 0, thi = 0;
    #pragma unroll
    for (int k = 0; k < SCAN_BLOCKS; ++k) {
        const ulonglong2 s = bsum[k];
        if (k < bid) { blo += s.x; bhi += s.y; }
        tlo += s.x; thi += s.y;
    }

    const ulonglong2 p = prefix[n];
    const u64 plo = p.x + blo;
    const u64 phi = p.y + bhi;

    const int4 ma = mask4[(size_t)n * 2];
    const int4 mb = mask4[(size_t)n * 2 + 1];
    const int me[8] = { ma.x, ma.y, ma.z, ma.w, mb.x, mb.y, mb.z, mb.w };

    int d[8];
    #pragma unroll
    for (int e = 0; e < E_NUM; ++e) {
        const u64 pk = (e < 4) ? plo : phi;
        const int r  = (int)((pk >> (16 * (e & 3))) & 0xFFFF);
        d[e] = me[e] ? r : -1;
        if (me[e]) out_tags[(size_t)e * N_TOK + r] = (float)n;
    }

    int4* dest4 = (int4*)dest;
    int4 d0; d0.x = d[0]; d0.y = d[1]; d0.z = d[2]; d0.w = d[3];
    int4 d1; d1.x = d[4]; d1.y = d[5]; d1.z = d[6]; d1.w = d[7];
    dest4[(size_t)n * 2]     = d0;
    dest4[(size_t)n * 2 + 1] = d1;

    // Per-expert counts from grand totals.
    int cnt[8];
    #pragma unroll
    for (int e = 0; e < E_NUM; ++e) {
        const u64 pk = (e < 4) ? tlo : thi;
        cnt[e] = (int)((pk >> (16 * (e & 3))) & 0xFFFF);
    }

    if (bid == 0 && t < E_NUM) {
        counts_i[t]   = cnt[t];
        out_counts[t] = (float)cnt[t];
    }

    // Tag pad fill: grid-strided over [count_e, N) per expert.
    const int g = bid * 256 + t;          // 0..8191
    #pragma unroll
    for (int e = 0; e < E_NUM; ++e) {
        for (int idx = cnt[e] + g; idx < N_TOK; idx += N_TOK) {
            out_tags[(size_t)e * N_TOK + idx] = 0.0f;
        }
    }
}

// K3: fused scatter + pad-fill — byte-identical to Round 2's hot kernel.
__global__ __launch_bounds__(256) void dispatch_scatter_kernel(
    const float4* __restrict__ x,       // [N, D/4]
    const float* __restrict__ score,    // [N, E]
    const int* __restrict__ dest,       // [N, E]
    const int* __restrict__ counts_i,   // [E]
    float4* __restrict__ out)           // [E*N, D/4]
{
    const int b = blockIdx.x;
    const int c = threadIdx.x;

    if (b < N_TOK) {
        const int n = b;
        const float4 xv = x[(size_t)n * D4 + c];
        #pragma unroll
        for (int e = 0; e < E_NUM; ++e) {
            const int r = dest[(size_t)n * E_NUM + e];   // uniform per block
            if (r >= 0) {
                const float s = score[(size_t)n * E_NUM + e];
                float4 v;
                v.x = xv.x * s;
                v.y = xv.y * s;
                v.z = xv.z * s;
                v.w = xv.w * s;
                out[((size_t)e * N_TOK + r) * D4 + c] = v;
            }
        }
    } else {
        const int row = b - N_TOK;          // e*N + r
        const int e   = row >> 13;
        const int r   = row & (N_TOK - 1);
        if (r >= counts_i[e]) {
            float4 z;
            z.x = 0.0f; z.y = 0.0f; z.z = 0.0f; z.w = 0.0f;
            out[(size_t)row * D4 + c] = z;
        }
    }
}

extern "C" void kernel_launch(void* const* d_in, const int* in_sizes, int n_in,
                              void* d_out, int out_size, void* d_ws, size_t ws_size,
                              hipStream_t stream) {
    const float* x        = (const float*)d_in[0];
    const int*   hot_mask = (const int*)d_in[1];
    const float* score    = (const float*)d_in[2];

    float* out        = (float*)d_out;
    float* out_data   = out;                                  // [E, N, D]
    float* out_tags   = out + (size_t)E_NUM * N_TOK * D_DIM;  // [E, N]
    float* out_counts = out_tags + (size_t)E_NUM * N_TOK;     // [E]

    ulonglong2* prefix = (ulonglong2*)d_ws;                   // [N]
    ulonglong2* bsum   = prefix + N_TOK;                      // [32]
    int* dest          = (int*)(bsum + SCAN_BLOCKS);          // [N, E]
    int* counts_i      = dest + (size_t)N_TOK * E_NUM;        // [E]

    scan_kernel<<<SCAN_BLOCKS, 256, 0, stream>>>(
        (const int4*)hot_mask, prefix, bsum);

    finalize_kernel<<<SCAN_BLOCKS, 256, 0, stream>>>(
        (const int4*)hot_mask, prefix, bsum, dest, counts_i, out_tags, out_counts);

    dispatch_scatter_kernel<<<N_TOK + E_NUM * N_TOK, 256, 0, stream>>>(
        (const float4*)x, score, dest, counts_i, (float4*)out_data);
}